// Round 14
// baseline (158.152 us; speedup 1.0000x reference)
//
#include <hip/hip_runtime.h>
#include <hip/hip_bf16.h>

// Flash attention fwd, masked, fp32 I/O, bf16 MFMA compute.
// n=8 heads, q=s=4096, d=v=64.
// Round 14: r13 (128-s phases, in-register P via one shfl_xor(32) exchange,
// 32x32x16 MFMA) with the merge-epilogue bug fixed: the s-half merge scratch
// used row stride 20 (correct for 16x16 tiles, lq<16) but 32x32 tiles have
// lq in 0..31 -> row collisions corrupted O (absmax 1.71). Stride is now 32,
// aliased exactly into Ksh (32KB); 2 lanes/bank on the epilogue = free.

#define NHEADS 8
#define QLEN   4096
#define SLEN   4096
#define DDIM   64
#define VDIM   64
#define PBLK   128                 // s per phase
#define QBLK   128
#define NPHASE (SLEN / PBLK)

typedef __bf16          bf16x4 __attribute__((ext_vector_type(4)));
typedef __bf16          bf16x8 __attribute__((ext_vector_type(8)));
typedef float           f32x4  __attribute__((ext_vector_type(4)));
typedef float           f32x16 __attribute__((ext_vector_type(16)));
typedef unsigned int    u32x4  __attribute__((ext_vector_type(4)));
typedef unsigned short  u16x4  __attribute__((ext_vector_type(4)));

#define KSWZ(s) (((s) & 7) << 4)
#define VSWZ(v) ((((v) >> 2) & 7) << 4)
#define CLAMPP(p) ((p) < NPHASE ? (p) : NPHASE - 1)

// LDS-only barrier: drain LDS ops, barrier, fence scheduler (rule #18).
#define LDS_BARRIER() do {                                          \
  asm volatile("s_waitcnt lgkmcnt(0)" ::: "memory");                \
  __builtin_amdgcn_s_barrier();                                     \
  __builtin_amdgcn_sched_barrier(0);                                \
} while (0)

__device__ __forceinline__ f32x16 zero16() {
  f32x16 z;
#pragma unroll
  for (int i = 0; i < 16; ++i) z[i] = 0.f;
  return z;
}

__device__ __forceinline__ unsigned short bfb(float x) {
  return __builtin_bit_cast(unsigned short, (__bf16)x);
}
__device__ __forceinline__ unsigned pk2(float a, float b) {
  return (unsigned)bfb(a) | ((unsigned)bfb(b) << 16);
}

// ---------------- in-kernel mask dtype detection ----------------
// i32 {0,1}: bytes 1,2 of every word zero -> 1.
// f32 {0,1.0f}: byte 0 of every word zero (0x3F800000 LE) -> 2.
// u8 bool: neither -> 0. Uniform across all lanes/waves/blocks.
__device__ __forceinline__ int detect_mfmt(const unsigned char* __restrict__ M) {
  const int lane = threadIdx.x & 63;
  u32x4 w = *((const u32x4*)M + lane);
  unsigned o = w[0] | w[1] | w[2] | w[3];
  unsigned comb = ((o & 0x00FFFF00u) ? 1u : 0u) | ((o & 0x000000FFu) ? 2u : 0u);
  comb |= __shfl_xor((int)comb, 1);  comb |= __shfl_xor((int)comb, 2);
  comb |= __shfl_xor((int)comb, 4);  comb |= __shfl_xor((int)comb, 8);
  comb |= __shfl_xor((int)comb, 16); comb |= __shfl_xor((int)comb, 32);
  return ((comb & 1u) == 0u) ? 1 : (((comb & 2u) == 0u) ? 2 : 0);
}

template<bool U8>
__global__ __launch_bounds__(512, 2)
void attn_fwd(const float* __restrict__ Qg, const float* __restrict__ Kg,
              const float* __restrict__ Vg, const unsigned char* __restrict__ Mg,
              float* __restrict__ Og)
{
  __shared__ __align__(16) unsigned short Ksh[2][128 * 64];  // [buf][s][d], KSWZ rows (16KB/buf)
  __shared__ __align__(16) unsigned short Vsh[2][64 * 128];  // [buf][v][s], VSWZ rows (16KB/buf)

  {
    const int mfmt = detect_mfmt(Mg);
    if (U8 ? (mfmt != 0) : (mfmt == 0)) return;   // other instantiation handles it
  }

  const int tid   = threadIdx.x;
  const int wave  = tid >> 6;
  const int lane  = tid & 63;
  const int qtile = wave & 3;     // q sub-tile (32 q) this wave owns
  const int shalf = wave >> 2;    // s-half (64 s of each 128-s phase)
  const int lq    = lane & 31;    // lane's q column within the tile
  const int h     = lane >> 5;    // lane half

  const int head = blockIdx.x;    // grid (8, 32): linear id % 8 == head -> one XCD per head
  const int qblk = blockIdx.y;

  const float* Qp = Qg + ((size_t)head * QLEN + (size_t)qblk * QBLK) * DDIM;
  const float* Kp = Kg + (size_t)head * SLEN * DDIM;
  const float* Vp = Vg + (size_t)head * SLEN * VDIM;
  float* Op = Og + ((size_t)head * QLEN + (size_t)qblk * QBLK) * DDIM;

  // ---- Q fragments (B-operand: col q = lq, k = 8h + i + 16kd), pre-scaled ----
  const float QSCALE = 0.125f * 1.44269504f;
  const int qrow = qtile * 32 + lq;
  bf16x8 qf[4];
#pragma unroll
  for (int kd = 0; kd < 4; ++kd) {
    const float* qp = Qp + (size_t)qrow * DDIM + 16 * kd + 8 * h;
    f32x4 a = *(const f32x4*)qp;
    f32x4 b = *(const f32x4*)(qp + 4);
    bf16x8 t;
#pragma unroll
    for (int j = 0; j < 4; ++j) { t[j] = (__bf16)(a[j] * QSCALE); t[4 + j] = (__bf16)(b[j] * QSCALE); }
    qf[kd] = t;
  }

  const size_t mbase = ((size_t)head * QLEN + (size_t)qblk * QBLK + qrow) * SLEN;
  const unsigned char* mrow8  = Mg + mbase;
  const unsigned*      mrow32 = (const unsigned*)Mg + mbase;

  f32x16 oacc[2];
  oacc[0] = zero16(); oacc[1] = zero16();
  float m_run = -INFINITY;
  float l_run = 0.f;

  // single K/V prefetch set (consumed same body), dual mask sets (dist-1 phase)
  f32x4 kp0, kp1, kp2, kp3, vp0, vp1, vp2, vp3;
  unsigned m8A[8],  m8B[8];      // U8: [4*st2+st]
  u32x4    m32A[8], m32B[8];     // !U8 (template DCE)

  // 512 threads stage 128x64: srow = (tid>>4) + 32it, d0 = (tid&15)*4
#define PREFETCH_KV(P)                                                         \
  {                                                                            \
    size_t b_ = (size_t)CLAMPP(P) * PBLK;                                      \
    int sr_ = tid >> 4, d0_ = (tid & 15) * 4;                                  \
    kp0 = *(const f32x4*)(Kp + (b_ + sr_     ) * DDIM + d0_);                  \
    kp1 = *(const f32x4*)(Kp + (b_ + sr_ + 32) * DDIM + d0_);                  \
    kp2 = *(const f32x4*)(Kp + (b_ + sr_ + 64) * DDIM + d0_);                  \
    kp3 = *(const f32x4*)(Kp + (b_ + sr_ + 96) * DDIM + d0_);                  \
    vp0 = *(const f32x4*)(Vp + (b_ + sr_     ) * VDIM + d0_);                  \
    vp1 = *(const f32x4*)(Vp + (b_ + sr_ + 32) * VDIM + d0_);                  \
    vp2 = *(const f32x4*)(Vp + (b_ + sr_ + 64) * VDIM + d0_);                  \
    vp3 = *(const f32x4*)(Vp + (b_ + sr_ + 96) * VDIM + d0_);                  \
  }

#define WRITE_ONE(BUF, KP, VP, IT)                                             \
  {                                                                            \
    int srow = (tid >> 4) + (IT) * 32;                                         \
    int d0   = (tid & 15) * 4;                                                 \
    bf16x4 kb;                                                                 \
    _Pragma("unroll") for (int j = 0; j < 4; ++j) kb[j] = (__bf16)KP[j];       \
    int koff = (srow * 128 + d0 * 2) ^ KSWZ(srow);                             \
    *(u16x4*)((char*)Ksh[BUF] + koff) = __builtin_bit_cast(u16x4, kb);         \
    _Pragma("unroll")                                                          \
    for (int j = 0; j < 4; ++j) {                                              \
      int v = d0 + j;                                                          \
      unsigned short b = __builtin_bit_cast(unsigned short, (__bf16)VP[j]);    \
      int voff = (v * 256 + srow * 2) ^ VSWZ(v);                               \
      *(unsigned short*)((char*)Vsh[BUF] + voff) = b;                          \
    }                                                                          \
  }

#define WRITE_KV(BUF)                                                          \
  WRITE_ONE(BUF, kp0, vp0, 0) WRITE_ONE(BUF, kp1, vp1, 1)                      \
  WRITE_ONE(BUF, kp2, vp2, 2) WRITE_ONE(BUF, kp3, vp3, 3)

  // lane's mask words for phase P: s = P*128 + 64*shalf + 32*st2 + 8*st + 4*h + r
#define LOAD_MASK(M8, M32, P)                                                  \
  if constexpr (U8) {                                                          \
    _Pragma("unroll")                                                          \
    for (int st2 = 0; st2 < 2; ++st2)                                          \
      _Pragma("unroll")                                                        \
      for (int st = 0; st < 4; ++st)                                           \
        M8[4 * st2 + st] = *(const unsigned*)(mrow8 + (size_t)CLAMPP(P) * PBLK \
                           + 64 * shalf + 32 * st2 + 8 * st + 4 * h);          \
  } else {                                                                     \
    _Pragma("unroll")                                                          \
    for (int st2 = 0; st2 < 2; ++st2)                                          \
      _Pragma("unroll")                                                        \
      for (int st = 0; st < 4; ++st)                                           \
        M32[4 * st2 + st] = *(const u32x4*)(mrow32 + (size_t)CLAMPP(P) * PBLK  \
                           + 64 * shalf + 32 * st2 + 8 * st + 4 * h);          \
  }

// One 32-s tile: QK^T -> mask/softmax -> in-register P exchange -> PV.
#define TILE(CUR, ST2, MU8, MU32) {                                            \
  /* QK^T: A = K rows (srow), B = Q^T; 4 k-steps over d */                     \
  f32x16 sacc = zero16();                                                      \
  int srow_ = 64 * shalf + 32 * (ST2) + lq;                                    \
  __builtin_amdgcn_s_setprio(1);                                               \
  _Pragma("unroll")                                                            \
  for (int kd = 0; kd < 4; ++kd) {                                             \
    int off = (srow_ * 128 + (32 * kd + 16 * h)) ^ KSWZ(srow_);                \
    bf16x8 kf = *(const bf16x8*)((const char*)Ksh[CUR] + off);                 \
    sacc = __builtin_amdgcn_mfma_f32_32x32x16_bf16(kf, qf[kd], sacc, 0, 0, 0); \
  }                                                                            \
  __builtin_amdgcn_s_setprio(0);                                               \
  /* mask + max (lane holds s_local = 8st+4h+r, q = qrow) */                   \
  float vals[4][4];                                                            \
  float mloc = -INFINITY;                                                      \
  _Pragma("unroll")                                                            \
  for (int st = 0; st < 4; ++st) {                                             \
    bool keep[4];                                                              \
    if constexpr (U8) {                                                        \
      unsigned w_ = MU8[4 * (ST2) + st];                                       \
      _Pragma("unroll")                                                        \
      for (int r = 0; r < 4; ++r) keep[r] = ((w_ >> (8 * r)) & 0xFFu) != 0u;   \
    } else {                                                                   \
      _Pragma("unroll")                                                        \
      for (int r = 0; r < 4; ++r) keep[r] = MU32[4 * (ST2) + st][r] != 0u;     \
    }                                                                          \
    _Pragma("unroll")                                                          \
    for (int r = 0; r < 4; ++r) {                                              \
      float v = keep[r] ? sacc[4 * st + r] : -1.0e9f;                          \
      vals[st][r] = v;                                                         \
      mloc = fmaxf(mloc, v);                                                   \
    }                                                                          \
  }                                                                            \
  mloc = fmaxf(mloc, __shfl_xor(mloc, 32));                                    \
  if (!__all(mloc <= m_run + 8.0f)) {      /* defer-max rescale */             \
    float m_new = fmaxf(m_run, mloc);                                          \
    float alpha = __builtin_amdgcn_exp2f(m_run - m_new);                       \
    l_run *= alpha;                                                            \
    _Pragma("unroll")                                                          \
    for (int vt = 0; vt < 2; ++vt)                                             \
      _Pragma("unroll")                                                        \
      for (int r = 0; r < 16; ++r) oacc[vt][r] *= alpha;                       \
    m_run = m_new;                                                             \
  }                                                                            \
  /* exp + pack: W[st] = (lo,hi) = packed bf16 of p[4st+0..3] */               \
  float lsum = 0.f;                                                            \
  unsigned wlo[4], whi[4];                                                     \
  _Pragma("unroll")                                                            \
  for (int st = 0; st < 4; ++st) {                                             \
    float p0 = __builtin_amdgcn_exp2f(vals[st][0] - m_run);                    \
    float p1 = __builtin_amdgcn_exp2f(vals[st][1] - m_run);                    \
    float p2 = __builtin_amdgcn_exp2f(vals[st][2] - m_run);                    \
    float p3 = __builtin_amdgcn_exp2f(vals[st][3] - m_run);                    \
    lsum += (p0 + p1) + (p2 + p3);                                             \
    wlo[st] = pk2(p0, p1);                                                     \
    whi[st] = pk2(p2, p3);                                                     \
  }                                                                            \
  lsum += __shfl_xor(lsum, 32);                                                \
  l_run += lsum;                                                               \
  /* PV: B-frag via one cross-half exchange per ks2. Lane (lq,h) needs        */ \
  /* P[q=lq][s=16ks2+8h+j]; it owns s=8st+4h+r -> keep st=2ks2+h, recv the    */ \
  /* partner's st=2ks2+(1-h). sigma-tolerant (V elem pos uses same k-slot).   */ \
  _Pragma("unroll")                                                            \
  for (int ks2 = 0; ks2 < 2; ++ks2) {                                          \
    unsigned slo = h ? wlo[2 * ks2] : wlo[2 * ks2 + 1];   /* send st=2ks2+1-h */ \
    unsigned shi = h ? whi[2 * ks2] : whi[2 * ks2 + 1];                        \
    unsigned rlo = __shfl_xor(slo, 32);                                        \
    unsigned rhi = __shfl_xor(shi, 32);                                        \
    unsigned klo = h ? wlo[2 * ks2 + 1] : wlo[2 * ks2];   /* keep st=2ks2+h */ \
    unsigned khi = h ? whi[2 * ks2 + 1] : whi[2 * ks2];                        \
    u32x4 fw;                                                                  \
    fw[0] = h ? rlo : klo;  fw[1] = h ? rhi : khi;                             \
    fw[2] = h ? klo : rlo;  fw[3] = h ? khi : rhi;                             \
    bf16x8 pf = __builtin_bit_cast(bf16x8, fw);                                \
    __builtin_amdgcn_s_setprio(1);                                             \
    _Pragma("unroll")                                                          \
    for (int vt = 0; vt < 2; ++vt) {                                           \
      int vrow = 32 * vt + lq;                                                 \
      int voff = (vrow * 256 + (128 * shalf + 64 * (ST2) + 32 * ks2 + 16 * h)) \
                 ^ VSWZ(vrow);                                                 \
      bf16x8 vf = *(const bf16x8*)((const char*)Vsh[CUR] + voff);              \
      oacc[vt] = __builtin_amdgcn_mfma_f32_32x32x16_bf16(vf, pf, oacc[vt], 0, 0, 0); \
    }                                                                          \
    __builtin_amdgcn_s_setprio(0);                                             \
  }                                                                            \
}

#define PHASE_BODY(P, CUR, MU8, MU32, ML8, ML32) {                             \
  PREFETCH_KV((P) + 1);                                                        \
  LOAD_MASK(ML8, ML32, (P) + 1);                                               \
  TILE(CUR, 0, MU8, MU32);                                                     \
  TILE(CUR, 1, MU8, MU32);                                                     \
  WRITE_KV((CUR) ^ 1);                                                         \
  LDS_BARRIER();                                                               \
}

  // prologue: phase 0 staged directly; its mask -> set A
  PREFETCH_KV(0);
  LOAD_MASK(m8A, m32A, 0);
  WRITE_KV(0);
  LDS_BARRIER();

  for (int pp = 0; pp < NPHASE; pp += 2) {
    PHASE_BODY(pp,     0, m8A, m32A, m8B, m32B);
    PHASE_BODY(pp + 1, 1, m8B, m32B, m8A, m32A);
  }

  // ---- merge the two s-halves via LDS (K/V buffers dead; alias them) ----
  // oacc reg -> v = 32vt + 8st + 4h + r (col q = lq).
  // Scratch: [qtile][64 v][32 q] floats = 32768 B == sizeof(Ksh) exactly.
  // (r13 bug: stride 20 < 32 caused row collisions; lq spans 0..31 here.)
  float* mO = (float*)&Ksh[0][0];
  float* mM = (float*)&Vsh[0][0];   // [qtile][2][32]: m then l (1KB)
  if (shalf == 1) {
#pragma unroll
    for (int vt = 0; vt < 2; ++vt) {
#pragma unroll
      for (int st = 0; st < 4; ++st) {
#pragma unroll
        for (int r = 0; r < 4; ++r) {
          int v = 32 * vt + 8 * st + 4 * h + r;
          mO[((size_t)qtile * 64 + v) * 32 + lq] = oacc[vt][4 * st + r];
        }
      }
    }
    if (h == 0) {
      mM[(qtile * 2 + 0) * 32 + lq] = m_run;
      mM[(qtile * 2 + 1) * 32 + lq] = l_run;
    }
  }
  LDS_BARRIER();
  if (shalf == 0) {
    float m1 = mM[(qtile * 2 + 0) * 32 + lq];
    float l1 = mM[(qtile * 2 + 1) * 32 + lq];
    float mm = fmaxf(m_run, m1);
    float a0 = __builtin_amdgcn_exp2f(m_run - mm);
    float a1 = __builtin_amdgcn_exp2f(m1 - mm);
    float inv = 1.0f / (l_run * a0 + l1 * a1);
    float* orow = Op + (size_t)qrow * VDIM;
#pragma unroll
    for (int vt = 0; vt < 2; ++vt) {
#pragma unroll
      for (int st = 0; st < 4; ++st) {
        int v0 = 32 * vt + 8 * st + 4 * h;
        f32x4 o;
#pragma unroll
        for (int r = 0; r < 4; ++r) {
          float o1 = mO[((size_t)qtile * 64 + v0 + r) * 32 + lq];
          o[r] = (oacc[vt][4 * st + r] * a0 + o1 * a1) * inv;
        }
        *(f32x4*)(orow + v0) = o;
      }
    }
  }
#undef PREFETCH_KV
#undef WRITE_ONE
#undef WRITE_KV
#undef LOAD_MASK
#undef TILE
#undef PHASE_BODY
}

extern "C" void kernel_launch(void* const* d_in, const int* in_sizes, int n_in,
                              void* d_out, int out_size, void* d_ws, size_t ws_size,
                              hipStream_t stream) {
  const float* Qg = (const float*)d_in[0];
  const float* Kg = (const float*)d_in[1];
  const float* Vg = (const float*)d_in[2];
  const unsigned char* Mg = (const unsigned char*)d_in[3];
  float* Og = (float*)d_out;

  dim3 grid(NHEADS, QLEN / QBLK);   // 256 blocks; linear id % 8 == head -> head-per-XCD
  dim3 block(512);
  attn_fwd<true ><<<grid, block, 0, stream>>>(Qg, Kg, Vg, Mg, Og);   // u8 bool mask
  attn_fwd<false><<<grid, block, 0, stream>>>(Qg, Kg, Vg, Mg, Og);   // i32/f32 mask
}